// Round 7
// baseline (1259.311 us; speedup 1.0000x reference)
//
#include <hip/hip_runtime.h>
#include <hip/hip_fp16.h>

// ============================================================================
// 2-layer LSTM (B=16384, T=128, F=12, H1=64, H2=128) + head, round 7.
// Changes vs R6 (881us, VALUBusy 69, MfmaUtil 22.5):
//  - R=32 rows/block, 512 blocks: R6 ran 4 sequential grid-rounds (1024 blocks
//    at 1 block/CU); per-block-step wall 4130cy vs ~1200cy issue work ->
//    latency-bound. 2 M-tiles per wave doubles independent chains per wave
//    (ILP) and halves round-serialization overhead.
//  - Weight pins now "+a" (AGPR): R6's "+v" pins forced AGPR<->VGPR round
//    trips (~60 VALU/step). Weights park in AGPRs; MFMA reads B from AGPR.
//  - One barrier per timestep, XOR-swizzled LDS, DPP qtrans4 (all from R6).
// ============================================================================

#define T_STEPS 128
#define F_IN    12
#define R       32      // batch rows per block (2 M-tiles of 16)

#define WF0_H8  (16*3*64)
#define WF1_H8  (32*6*64)
#define WH_TOTAL_HALVES ((WF0_H8 + WF1_H8)*8)   // 245760 B

typedef _Float16 half8 __attribute__((ext_vector_type(8)));
typedef _Float16 half4 __attribute__((ext_vector_type(4)));
typedef float   floatx4 __attribute__((ext_vector_type(4)));
typedef int     intx4  __attribute__((ext_vector_type(4)));

__device__ __forceinline__ float vexp2(float x){
  float r; asm("v_exp_f32 %0, %1" : "=v"(r) : "v"(x)); return r;
}
__device__ __forceinline__ float vrcp(float x){
  float r; asm("v_rcp_f32 %0, %1" : "=v"(r) : "v"(x)); return r;
}
__device__ __forceinline__ float sigf(float x){        // sigmoid
  return vrcp(1.0f + vexp2(-1.4426950408889634f * x));
}
__device__ __forceinline__ float tanhf_(float x){      // tanh
  return fmaf(2.0f, vrcp(1.0f + vexp2(-2.8853900817779268f * x)), -1.0f);
}

// DPP quad_perm helpers.
__device__ __forceinline__ float qpx1(float v){
  return __int_as_float(__builtin_amdgcn_update_dpp(
      0, __float_as_int(v), 0xB1 /*[1,0,3,2]*/, 0xF, 0xF, true));
}
__device__ __forceinline__ float qpx2(float v){
  return __int_as_float(__builtin_amdgcn_update_dpp(
      0, __float_as_int(v), 0x4E /*[2,3,0,1]*/, 0xF, 0xF, true));
}
// 4x4 transpose across a lane quad (verified R4-R6).
__device__ __forceinline__ floatx4 qtrans4(floatx4 s, int g){
  float e0 = qpx1(s[1]), e1 = qpx1(s[0]), e2 = qpx1(s[3]), e3 = qpx1(s[2]);
  const bool lo = (g & 1);
  float m0 = lo ? e0   : s[0];
  float m1 = lo ? s[1] : e1;
  float m2 = lo ? e2   : s[2];
  float m3 = lo ? s[3] : e3;
  float f0 = qpx2(m2), f1 = qpx2(m3), f2 = qpx2(m0), f3 = qpx2(m1);
  const bool hi = (g & 2);
  floatx4 d;
  d[0] = hi ? f0 : m0;
  d[1] = hi ? f1 : m1;
  d[2] = hi ? m2 : f2;
  d[3] = hi ? m3 : f3;
  return d;
}

// ---------------------------------------------------------------------------
// Prep: pack fp16 MFMA B-fragments (PERMUTED columns p=4h+g) + fused biases.
// ---------------------------------------------------------------------------
__global__ void prep_kernel(const float* __restrict__ Wih0, const float* __restrict__ Whh0,
                            const float* __restrict__ bih0, const float* __restrict__ bhh0,
                            const float* __restrict__ Wih1, const float* __restrict__ Whh1,
                            const float* __restrict__ bih1, const float* __restrict__ bhh1,
                            _Float16* __restrict__ wh, float* __restrict__ bs) {
  int tid = blockIdx.x * 256 + threadIdx.x;
  if (tid < WF0_H8) {
    int lane = tid & 63; int kt = (tid >> 6) % 3; int ct = tid / (64*3);
    int p = ct*16 + (lane & 15);
    int col = (p & 3)*64 + (p >> 2);          // orig row of W0cat: gate*64 + hidden
    int kbase = kt*32 + (lane >> 4)*8;
    #pragma unroll
    for (int j = 0; j < 8; ++j) {
      int k = kbase + j; float w = 0.0f;
      if (k < 12) w = Wih0[col*12 + k];
      else if (k < 76) w = Whh0[col*64 + (k-12)];
      wh[tid*8 + j] = (_Float16)w;
    }
  } else if (tid < WF0_H8 + WF1_H8) {
    int t2 = tid - WF0_H8;
    int lane = t2 & 63; int kt = (t2 >> 6) % 6; int ct = t2 / (64*6);
    int p = ct*16 + (lane & 15);
    int col = (p & 3)*128 + (p >> 2);         // gate*128 + hidden
    int kbase = kt*32 + (lane >> 4)*8;
    #pragma unroll
    for (int j = 0; j < 8; ++j) {
      int k = kbase + j;
      float w = (k < 64) ? Wih1[col*64 + k] : Whh1[col*128 + (k-64)];
      wh[WF0_H8*8 + t2*8 + j] = (_Float16)w;
    }
  } else if (tid < WF0_H8 + WF1_H8 + 768) {
    int t3 = tid - (WF0_H8 + WF1_H8);
    if (t3 < 256) { int col = (t3 & 3)*64 + (t3 >> 2);  bs[t3] = bih0[col] + bhh0[col]; }
    else { int p1 = t3 - 256; int col = (p1 & 3)*128 + (p1 >> 2); bs[t3] = bih1[col] + bhh1[col]; }
  }
}

// ---------------------------------------------------------------------------
// Main kernel: 1024 threads (16 waves), 32 rows/block, 512 blocks (2 rounds).
// st0[2][32][128]h: per row [x12|h0 64|zeros], XOR-swizzled 8-half blocks.
// st1[32][512]h:    per row [h0_p0 64|h0_p1 64|h1_p0 128|h1_p1 128].
// ---------------------------------------------------------------------------
__global__ __launch_bounds__(1024, 1)
void lstm_kernel(const float* __restrict__ x, const _Float16* __restrict__ wh,
                 const float* __restrict__ bs,
                 const float* __restrict__ Wd1, const float* __restrict__ bd1,
                 const float* __restrict__ Wd2, const float* __restrict__ bd2,
                 float* __restrict__ out) {
  __shared__ __align__(16) _Float16 st0[2*R*128];   // 16384 B
  __shared__ __align__(16) _Float16 st1[R*512];     // 32768 B
  __shared__ float hbuf[R*132];                     // 16896 B
  __shared__ float red[R*33];                       // 4224 B  -> ~70 KB

  const int tid  = threadIdx.x;
  const int w    = tid >> 6;
  const int lane = tid & 63;
  const int l15  = lane & 15;
  const int lg   = lane >> 4;            // 0..3
  const int a    = l15 >> 2;
  const int g    = l15 & 3;
  const int r    = lg*4 + g;             // cell batch-row within M-tile
  const int rowbase = blockIdx.x * R;

  // Swizzled address helpers (in halves).
  auto st0a = [](int buf, int row, int blk){
    return (buf*R + row)*128 + (((blk ^ (row & 7)) << 3)); };
  auto st0s = [](int buf, int row, int idx){
    return (buf*R + row)*128 + ((((idx >> 3) ^ (row & 7)) << 3) | (idx & 7)); };
  auto st1a = [](int row, int blk){
    return row*512 + (((blk ^ (row & 7)) << 3)); };
  auto st1s = [](int row, int idx){
    return row*512 + ((((idx >> 3) ^ (row & 7)) << 3) | (idx & 7)); };

  // ---- weights -> AGPR-parked registers, pinned in place ("+a") ----
  const intx4* whi = (const intx4*)wh;
  intx4 wb0i[3];
  #pragma unroll
  for (int kt = 0; kt < 3; ++kt) wb0i[kt] = whi[(w*3 + kt)*64 + lane];
  intx4 wb1i[2][6];
  #pragma unroll
  for (int i = 0; i < 2; ++i)
    #pragma unroll
    for (int kt = 0; kt < 6; ++kt) wb1i[i][kt] = whi[WF0_H8 + ((2*w+i)*6 + kt)*64 + lane];
  float b0 = bs[w*16 + l15];
  float b1[2];
  #pragma unroll
  for (int i = 0; i < 2; ++i) b1[i] = bs[256 + (2*w+i)*16 + l15];

  // Register cell state: 2 M-tiles x (1 layer0 cell + 2 layer1 cells).
  float c0_0 = 0.0f, c0_1 = 0.0f;
  float c1_00 = 0.0f, c1_01 = 0.0f;   // mt0: coltile 2w, 2w+1
  float c1_10 = 0.0f, c1_11 = 0.0f;   // mt1
  const int h0i = 4*w + a;
  const int h1a = 8*w + a;
  const int h1b = 8*w + 4 + a;

  // ---- zero-init LDS ----
  for (int i = tid; i < (2*R*128)/2; i += 1024) ((int*)st0)[i] = 0;
  for (int i = tid; i < (R*512)/2;   i += 1024) ((int*)st1)[i] = 0;
  __syncthreads();
  const int xr = tid / 3, xq = tid % 3;     // 96 active threads for x staging
  if (tid < 96) {
    float4 v0 = *(const float4*)&x[((size_t)(rowbase + xr)*T_STEPS + 0)*F_IN + xq*4];
    float4 v1 = *(const float4*)&x[((size_t)(rowbase + xr)*T_STEPS + 1)*F_IN + xq*4];
    half4 h40 = {(_Float16)v0.x, (_Float16)v0.y, (_Float16)v0.z, (_Float16)v0.w};
    half4 h41 = {(_Float16)v1.x, (_Float16)v1.y, (_Float16)v1.z, (_Float16)v1.w};
    *(half4*)&st0[st0s(0, xr, xq*4)] = h40;
    *(half4*)&st0[st0s(1, xr, xq*4)] = h41;
  }
  __syncthreads();

  // ---- layer-0 step for M-tile mt ----
  auto do_A = [&](int tt, int mt, float& c0ref){
    const int pr = tt & 1;
    const int row16 = mt*16;
    floatx4 acc = {b0, b0, b0, b0};
    #pragma unroll
    for (int kt = 0; kt < 3; ++kt) {
      half8 af = *(const half8*)&st0[st0a(pr, row16 + l15, kt*4 + lg)];
      acc = __builtin_amdgcn_mfma_f32_16x16x32_f16(af, __builtin_bit_cast(half8, wb0i[kt]), acc, 0, 0, 0);
    }
    floatx4 d = qtrans4(acc, g);
    c0ref = fmaf(sigf(d[1]), c0ref, sigf(d[0]) * tanhf_(d[2]));
    float h0v = sigf(d[3]) * tanhf_(c0ref);
    _Float16 hh = (_Float16)h0v;
    const int row = row16 + r;
    st0[st0s(pr^1, row, 12 + h0i)] = hh;
    st1[st1s(row, pr*64 + h0i)]    = hh;
  };

  // ---- layer-1 step for M-tile mt ----
  auto do_C = [&](int tt, int mt, float& c1x, float& c1y){
    const int pr = tt & 1;
    const int row16 = mt*16;
    floatx4 a0 = {b1[0], b1[0], b1[0], b1[0]};
    floatx4 a1 = {b1[1], b1[1], b1[1], b1[1]};
    #pragma unroll
    for (int kt = 0; kt < 6; ++kt) {
      const int blk = (kt < 2) ? (pr*8 + kt*4 + lg)
                               : (16 + (pr^1)*16 + (kt-2)*4 + lg);
      half8 af = *(const half8*)&st1[st1a(row16 + l15, blk)];
      a0 = __builtin_amdgcn_mfma_f32_16x16x32_f16(af, __builtin_bit_cast(half8, wb1i[0][kt]), a0, 0, 0, 0);
      a1 = __builtin_amdgcn_mfma_f32_16x16x32_f16(af, __builtin_bit_cast(half8, wb1i[1][kt]), a1, 0, 0, 0);
    }
    floatx4 da = qtrans4(a0, g);
    floatx4 db = qtrans4(a1, g);
    c1x = fmaf(sigf(da[1]), c1x, sigf(da[0]) * tanhf_(da[2]));
    c1y = fmaf(sigf(db[1]), c1y, sigf(db[0]) * tanhf_(db[2]));
    float h1v0 = sigf(da[3]) * tanhf_(c1x);
    float h1v1 = sigf(db[3]) * tanhf_(c1y);
    const int row = row16 + r;
    st1[st1s(row, 128 + pr*128 + h1a)] = (_Float16)h1v0;
    st1[st1s(row, 128 + pr*128 + h1b)] = (_Float16)h1v1;
    if (tt == T_STEPS - 1) { hbuf[row*132 + h1a] = h1v0; hbuf[row*132 + h1b] = h1v1; }
  };

  // ---- prologue: A(0) both tiles; then phases {C(t) || A(t+1)}, ONE barrier
  do_A(0, 0, c0_0); do_A(0, 1, c0_1);
  __syncthreads();

  for (int t = 0; t < T_STEPS; t += 2) {
    // Pin weights in AGPRs (no copies; forbids remat/spill of the frags).
    #pragma unroll
    for (int kt = 0; kt < 3; ++kt) asm volatile("" : "+a"(wb0i[kt]));
    #pragma unroll
    for (int i = 0; i < 2; ++i)
      #pragma unroll
      for (int kt = 0; kt < 6; ++kt) asm volatile("" : "+a"(wb1i[i][kt]));
    asm volatile("" : "+v"(b0), "+v"(b1[0]), "+v"(b1[1]));

    #pragma unroll
    for (int hl = 0; hl < 2; ++hl) {
      const int tt = t + hl;
      const int pr = hl;               // tt & 1
      float4 xv = {0.0f, 0.0f, 0.0f, 0.0f};
      const bool dopre = (tt + 2 < T_STEPS);
      if (tid < 96 && dopre)           // issue x(tt+2) load early
        xv = *(const float4*)&x[((size_t)(rowbase + xr)*T_STEPS + (tt+2))*F_IN + xq*4];

      do_C(tt, 0, c1_00, c1_01);
      do_C(tt, 1, c1_10, c1_11);
      if (tt + 1 < T_STEPS) { do_A(tt+1, 0, c0_0); do_A(tt+1, 1, c0_1); }

      if (tid < 96 && dopre) {
        half4 h4 = {(_Float16)xv.x, (_Float16)xv.y, (_Float16)xv.z, (_Float16)xv.w};
        *(half4*)&st0[st0s(pr, xr, xq*4)] = h4;
      }
      __syncthreads();
    }
  }

  // ---------- Head: out[r] = b_d2 + Wd2 @ (b_d1 + Wd1 @ h1[r]) ----------
  {
    const int hr = tid & 31, jg = tid >> 5;   // 32 j-groups of 4
    float partial = 0.0f;
    #pragma unroll
    for (int jj = 0; jj < 4; ++jj) {
      int j = jg*4 + jj;
      float dacc = bd1[j];
      const float4* wrow = (const float4*)&Wd1[j*128];
      #pragma unroll 8
      for (int k4 = 0; k4 < 32; ++k4) {
        float4 wv = wrow[k4];
        const float4 hv = *(const float4*)&hbuf[hr*132 + k4*4];
        dacc = fmaf(wv.x, hv.x, dacc); dacc = fmaf(wv.y, hv.y, dacc);
        dacc = fmaf(wv.z, hv.z, dacc); dacc = fmaf(wv.w, hv.w, dacc);
      }
      partial = fmaf(Wd2[j], dacc, partial);
    }
    red[hr*33 + jg] = partial;
  }
  __syncthreads();
  if (tid < R) {
    float ssum = bd2[0];
    #pragma unroll
    for (int k = 0; k < 32; ++k) ssum += red[tid*33 + k];
    out[rowbase + tid] = ssum;
  }
}

extern "C" void kernel_launch(void* const* d_in, const int* in_sizes, int n_in,
                              void* d_out, int out_size, void* d_ws, size_t ws_size,
                              hipStream_t stream) {
  const float* x    = (const float*)d_in[0];
  const float* Wih0 = (const float*)d_in[1];
  const float* Whh0 = (const float*)d_in[2];
  const float* bih0 = (const float*)d_in[3];
  const float* bhh0 = (const float*)d_in[4];
  const float* Wih1 = (const float*)d_in[5];
  const float* Whh1 = (const float*)d_in[6];
  const float* bih1 = (const float*)d_in[7];
  const float* bhh1 = (const float*)d_in[8];
  const float* Wd1  = (const float*)d_in[9];
  const float* bd1  = (const float*)d_in[10];
  const float* Wd2  = (const float*)d_in[11];
  const float* bd2  = (const float*)d_in[12];
  float* out = (float*)d_out;

  _Float16* wh  = (_Float16*)d_ws;
  float*    bsv = (float*)((char*)d_ws + (size_t)WH_TOTAL_HALVES * 2);

  prep_kernel<<<63, 256, 0, stream>>>(Wih0, Whh0, bih0, bhh0, Wih1, Whh1, bih1, bhh1, wh, bsv);
  // 16384 rows / 32 per block = 512 blocks (2 resident rounds)
  lstm_kernel<<<512, 1024, 0, stream>>>(x, wh, bsv, Wd1, bd1, Wd2, bd2, out);
}